// Round 6
// baseline (245.682 us; speedup 1.0000x reference)
//
#include <hip/hip_runtime.h>
#include <math.h>

#define B_ 4
#define S_ 2048
#define E_ 1024
#define H_ 16
#define D_ 64
#define M_TOT 8192
#define N_QKV 3072
#define K_ 1024

typedef __attribute__((ext_vector_type(8))) __bf16 bf16x8;
typedef __attribute__((ext_vector_type(2))) __bf16 bf16x2;
typedef __attribute__((ext_vector_type(8))) unsigned short u16x8;
typedef __attribute__((ext_vector_type(16))) float f32x16;

static __device__ __forceinline__ float bf2f(unsigned short u) {
  union { unsigned int u; float f; } x; x.u = ((unsigned int)u) << 16;
  return x.f;
}
// RNE f32->bf16 pair packed into one u32 (compiler emits v_cvt_pk_bf16_f32)
static __device__ __forceinline__ unsigned int pack_bf16(float lo, float hi) {
  bf16x2 t; t[0] = (__bf16)lo; t[1] = (__bf16)hi;
  return __builtin_bit_cast(unsigned int, t);
}
// v_permlane32_swap_b32: a'={a.lo,b.lo}, b'={a.hi,b.hi} (verified R3->R4)
static __device__ __forceinline__ void perm32swap(unsigned int& a, unsigned int& b) {
  asm volatile("v_permlane32_swap_b32 %0, %1" : "+v"(a), "+v"(b));
}

static __device__ __forceinline__ void gload16(const void* g, void* l) {
  __builtin_amdgcn_global_load_lds(
      (const __attribute__((address_space(1))) void*)g,
      (__attribute__((address_space(3))) void*)l, 16, 0, 0);
}

// ---------------------------------------------------------------------------
// Converters: fp32 -> bf16 (flat), and fp32 [K][N] -> bf16 [N][K] (transpose)
// ---------------------------------------------------------------------------
__global__ __launch_bounds__(256) void cvt_k(const float* __restrict__ in,
                                             unsigned short* __restrict__ out,
                                             int n8) {
  int i = blockIdx.x * 256 + threadIdx.x;
  if (i >= n8) return;
  float4 a = *reinterpret_cast<const float4*>(in + (size_t)i * 8);
  float4 b = *reinterpret_cast<const float4*>(in + (size_t)i * 8 + 4);
  uint4 o;
  o.x = pack_bf16(a.x, a.y); o.y = pack_bf16(a.z, a.w);
  o.z = pack_bf16(b.x, b.y); o.w = pack_bf16(b.z, b.w);
  *reinterpret_cast<uint4*>(out + (size_t)i * 8) = o;
}

__global__ __launch_bounds__(256) void tcvt_k(const float* __restrict__ in,
                                              unsigned short* __restrict__ out,
                                              int K, int N) {
  __shared__ float t[64][65];
  int n0 = blockIdx.x * 64, k0 = blockIdx.y * 64;
  int r = threadIdx.x >> 4, c = (threadIdx.x & 15) * 4;
#pragma unroll
  for (int it = 0; it < 4; ++it) {
    float4 v = *reinterpret_cast<const float4*>(&in[(size_t)(k0 + r + it * 16) * N + n0 + c]);
    t[r + it * 16][c + 0] = v.x; t[r + it * 16][c + 1] = v.y;
    t[r + it * 16][c + 2] = v.z; t[r + it * 16][c + 3] = v.w;
  }
  __syncthreads();
#pragma unroll
  for (int it = 0; it < 4; ++it) {
    int rr = r + it * 16;
    uint2 o;
    o.x = pack_bf16(t[c + 0][rr], t[c + 1][rr]);
    o.y = pack_bf16(t[c + 2][rr], t[c + 3][rr]);
    *reinterpret_cast<uint2*>(&out[(size_t)(n0 + rr) * K + k0 + c]) = o;
  }
}

// ---------------------------------------------------------------------------
// bf16 MFMA GEMM: C[M][N] = A[M][K] @ BT[N][K]^T (+bias).
// Tile 128x256, BK=32, 4 waves x (4x2) 32x32x16 frags; global_load_lds
// staging with pre-swizzled global source (slot ^ ((row>>1)&3)).
// MODE 0: Q,K parts -> qkv [2][B][H][S][D] bf16; V part -> vT [B][H][D][S]
//         bf16 (transposed store so attention stages V^T directly).
// MODE 1: fp32 C + bias.
// ---------------------------------------------------------------------------
template <int MODE>
__global__ __launch_bounds__(256) void gemm_k(
    const unsigned short* __restrict__ A, const unsigned short* __restrict__ BT,
    const float* __restrict__ bias, void* __restrict__ Cout,
    unsigned short* __restrict__ vT) {
  __shared__ __attribute__((aligned(128))) char lds[2][24576];
  const int tid = threadIdx.x;
  const int wv = tid >> 6, lane = tid & 63;
  const int ln = lane & 31, hh = lane >> 5;
  const int m0 = blockIdx.y * 128, n0 = blockIdx.x * 256;
  const int r4 = lane >> 2, slot = lane & 3;

  const char* Ab = (const char*)A;
  const char* Bb = (const char*)BT;
  size_t a_off[2], b_off[4];
#pragma unroll
  for (int i = 0; i < 2; ++i) {
    int r = wv * 32 + i * 16 + r4;
    a_off[i] = (size_t)(m0 + r) * (K_ * 2) + (size_t)((slot ^ ((r >> 1) & 3)) * 16);
  }
#pragma unroll
  for (int j = 0; j < 4; ++j) {
    int r = wv * 64 + j * 16 + r4;
    b_off[j] = (size_t)(n0 + r) * (K_ * 2) + (size_t)((slot ^ ((r >> 1) & 3)) * 16);
  }

  f32x16 acc[4][2];
#pragma unroll
  for (int gr = 0; gr < 4; ++gr)
#pragma unroll
    for (int gc = 0; gc < 2; ++gc)
#pragma unroll
      for (int e = 0; e < 16; ++e) acc[gr][gc][e] = 0.f;

#define STAGE(dst, tt)                                                        \
  do {                                                                        \
    char* _d = (dst);                                                         \
    size_t _ko = (size_t)(tt) * 64;                                           \
    _Pragma("unroll") for (int i = 0; i < 2; ++i)                             \
        gload16(Ab + a_off[i] + _ko, _d + (wv * 32 + i * 16) * 64);           \
    _Pragma("unroll") for (int j = 0; j < 4; ++j)                             \
        gload16(Bb + b_off[j] + _ko, _d + 8192 + (wv * 64 + j * 16) * 64);    \
  } while (0)

  STAGE(&lds[0][0], 0);
  __syncthreads();
  for (int t = 0; t < K_ / 32; ++t) {
    char* cur = &lds[t & 1][0];
    char* nxt = &lds[(t + 1) & 1][0];
    if (t + 1 < K_ / 32) STAGE(nxt, t + 1);
#pragma unroll
    for (int s = 0; s < 2; ++s) {
      const int cb = s * 32 + hh * 16;
      bf16x8 af[4], bfr[2];
#pragma unroll
      for (int gr = 0; gr < 4; ++gr) {
        int row = gr * 32 + ln;
        af[gr] = *reinterpret_cast<const bf16x8*>(
            cur + row * 64 + (cb ^ (((row >> 1) & 3) << 4)));
      }
#pragma unroll
      for (int gc = 0; gc < 2; ++gc) {
        int row = wv * 64 + gc * 32 + ln;
        bfr[gc] = *reinterpret_cast<const bf16x8*>(
            cur + 8192 + row * 64 + (cb ^ (((row >> 1) & 3) << 4)));
      }
#pragma unroll
      for (int gr = 0; gr < 4; ++gr)
#pragma unroll
        for (int gc = 0; gc < 2; ++gc)
          acc[gr][gc] = __builtin_amdgcn_mfma_f32_32x32x16_bf16(
              af[gr], bfr[gc], acc[gr][gc], 0, 0, 0);
    }
    __syncthreads();
  }
#undef STAGE

  // epilogue. C row = m0 + gr*32 + 4*hh + (r&3) + 8*(r>>2); col = n0+wv*64+gc*32+ln
  const int ncol0 = n0 + wv * 64;
  if (MODE == 0) {
    unsigned short* qkv = (unsigned short*)Cout;
#pragma unroll
    for (int gc = 0; gc < 2; ++gc) {
      int n = ncol0 + gc * 32 + ln;
      float bv = bias[n];
      int which = n >> 10, h = (n >> 6) & 15, d = n & 63;
      if (which < 2) {  // Q or K: [which][bi][h][si][d]
        unsigned short* base =
            qkv + (((size_t)which * B_ * H_ + h) * S_) * D_ + d;
#pragma unroll
        for (int gr = 0; gr < 4; ++gr)
#pragma unroll
          for (int r = 0; r < 16; r += 2) {
            int m = m0 + gr * 32 + 4 * hh + (r & 3) + 8 * (r >> 2);
            unsigned int w = pack_bf16(acc[gr][gc][r] + bv, acc[gr][gc][r + 1] + bv);
            int bi = m >> 11, si = m & 2047;
            size_t off = ((size_t)bi * H_ * S_ + si) * D_;
            base[off] = (unsigned short)w;
            base[off + D_] = (unsigned short)(w >> 16);
          }
      } else {  // V: transposed store vT[bi][h][d][si] (4 consecutive si)
        unsigned short* vbase = vT + ((size_t)h * D_ + d) * S_;
#pragma unroll
        for (int gr = 0; gr < 4; ++gr)
#pragma unroll
          for (int rq = 0; rq < 4; ++rq) {
            int mb = m0 + gr * 32 + 4 * hh + 8 * rq;
            int bi = mb >> 11, si = mb & 2047;
            uint2 w;
            w.x = pack_bf16(acc[gr][gc][rq * 4 + 0] + bv, acc[gr][gc][rq * 4 + 1] + bv);
            w.y = pack_bf16(acc[gr][gc][rq * 4 + 2] + bv, acc[gr][gc][rq * 4 + 3] + bv);
            *reinterpret_cast<uint2*>(vbase + (size_t)bi * H_ * D_ * S_ + si) = w;
          }
      }
    }
  } else {
    float* out = (float*)Cout;
#pragma unroll
    for (int gc = 0; gc < 2; ++gc) {
      int n = ncol0 + gc * 32 + ln;
      float bv = bias[n];
#pragma unroll
      for (int gr = 0; gr < 4; ++gr)
#pragma unroll
        for (int r = 0; r < 16; ++r) {
          int m = m0 + gr * 32 + 4 * hh + (r & 3) + 8 * (r >> 2);
          out[(size_t)m * E_ + n] = acc[gr][gc][r] + bv;
        }
    }
  }
}

// ---------------------------------------------------------------------------
// bf16 MFMA flash attention. K AND Vt staged via global_load_lds (zero
// staging VALU). K LDS: [32 r][8 slots 16B], content slot s at physical
// s^(r&7) (pre-swizzled global source). Vt LDS: [64 d][4 slots 16B],
// content slot s at physical s^((d>>1)&3) — same scheme as the GEMM tiles.
// PV reads are plain ds_read_b128 (R4-proven geometry). setprio (T5).
// ---------------------------------------------------------------------------
__global__ __launch_bounds__(256, 4) void attn_k(
    const unsigned short* __restrict__ qkv, const unsigned short* __restrict__ vT,
    unsigned short* __restrict__ ctx) {
  __shared__ __attribute__((aligned(128))) char lds[2][8192];  // 4KB K + 4KB Vt
  const int tid = threadIdx.x;
  const int wv = tid >> 6;
  const int lane = tid & 63;
  const int ln = lane & 31;
  const int hh = lane >> 5;
  const int q0 = blockIdx.x * 128;
  const int bh = blockIdx.y;
  const int b = bh >> 4, head = bh & 15;
  const size_t SZ = (size_t)B_ * H_ * S_ * D_;
  const size_t plane = ((size_t)b * H_ + head) * (size_t)S_ * D_;
  const unsigned short* Qp = qkv + plane;
  const unsigned short* Kp = qkv + SZ + plane;
  const unsigned short* Vp = vT + ((size_t)b * H_ + head) * (size_t)D_ * S_;

  // Q in registers, pre-scaled by (1/8)*log2(e)
  const float SC = 0.125f * 1.4426950408889634f;
  const int qrow = q0 + wv * 32 + ln;
  bf16x8 qf[4];
#pragma unroll
  for (int db = 0; db < 4; ++db) {
    u16x8 qr = *reinterpret_cast<const u16x8*>(Qp + (size_t)qrow * D_ + db * 16 + hh * 8);
    bf16x8 qs;
#pragma unroll
    for (int j = 0; j < 8; ++j) qs[j] = (__bf16)(bf2f(qr[j]) * SC);
    qf[db] = qs;
  }

  // staging source offsets (elements); LDS dests are linear tid*16
  // K: thread t -> row r=t>>3, phys slot p=t&7, content slot p^(r&7)
  const size_t ksrc = (size_t)(tid >> 3) * 64 +
                      (size_t)(((tid & 7) ^ ((tid >> 3) & 7)) * 8);
  // Vt: thread t -> row d=t>>2, phys slot p=t&3, content slot p^((d>>1)&3)
  const size_t vsrc = (size_t)(tid >> 2) * S_ +
                      (size_t)(((tid & 3) ^ ((tid >> 3) & 3)) * 8);

#define ASTAGE(bsel, tt)                                                      \
  do {                                                                        \
    char* _d = &lds[(bsel)][0];                                               \
    gload16(Kp + (size_t)(tt) * 2048 + ksrc, _d + tid * 16);                  \
    gload16(Vp + (size_t)(tt) * 32 + vsrc, _d + 4096 + tid * 16);             \
  } while (0)

  ASTAGE(0, 0);
  __syncthreads();

  f32x16 acc0, acc1;
#pragma unroll
  for (int e = 0; e < 16; ++e) { acc0[e] = 0.f; acc1[e] = 0.f; }
  float mrun = -1e30f, lrun = 0.f;
  const int xo = (ln >> 1) & 3;

  for (int t = 0; t < 64; ++t) {
    const int cb = t & 1;
    if (t + 1 < 64) ASTAGE(cb ^ 1, t + 1);
    const char* cur = &lds[cb][0];
    // QK^T -> S^T[key][q]
    f32x16 st;
#pragma unroll
    for (int e = 0; e < 16; ++e) st[e] = 0.f;
    __builtin_amdgcn_s_setprio(1);
#pragma unroll
    for (int db = 0; db < 4; ++db) {
      bf16x8 kf = *reinterpret_cast<const bf16x8*>(
          cur + ln * 128 + ((((db << 1) | hh) ^ (ln & 7)) << 4));
      st = __builtin_amdgcn_mfma_f32_32x32x16_bf16(kf, qf[db], st, 0, 0, 0);
    }
    __builtin_amdgcn_s_setprio(0);
    // Vt fragments (issue early; lgkm latency hides under softmax VALU)
    const char* vb_ = cur + 4096;
    bf16x8 vA = *reinterpret_cast<const bf16x8*>(vb_ + ln * 64 + ((hh ^ xo) << 4));
    bf16x8 vB = *reinterpret_cast<const bf16x8*>(vb_ + ln * 64 + (((2 + hh) ^ xo) << 4));
    bf16x8 vC = *reinterpret_cast<const bf16x8*>(vb_ + (ln + 32) * 64 + ((hh ^ xo) << 4));
    bf16x8 vD = *reinterpret_cast<const bf16x8*>(vb_ + (ln + 32) * 64 + (((2 + hh) ^ xo) << 4));
    // online softmax (exp2 domain)
    float m1 = fmaxf(fmaxf(st[0], st[1]), st[2]);
    float m2 = fmaxf(fmaxf(st[3], st[4]), st[5]);
    float m3 = fmaxf(fmaxf(st[6], st[7]), st[8]);
    float m4 = fmaxf(fmaxf(st[9], st[10]), st[11]);
    float m5 = fmaxf(fmaxf(st[12], st[13]), st[14]);
    float tm = fmaxf(fmaxf(fmaxf(m1, m2), fmaxf(m3, m4)), fmaxf(m5, st[15]));
    tm = fmaxf(tm, __shfl_xor(tm, 32, 64));
    if (!__all(tm <= mrun + 8.0f)) {  // defer-max (T13)
      float newm = fmaxf(mrun, tm);
      float alpha = exp2f(mrun - newm);
      mrun = newm;
      lrun *= alpha;
      acc0 *= alpha;
      acc1 *= alpha;
    }
    float p[16];
#pragma unroll
    for (int r = 0; r < 16; ++r) p[r] = exp2f(st[r] - mrun);
    float s0 = (p[0] + p[1]) + (p[2] + p[3]);
    float s1 = (p[4] + p[5]) + (p[6] + p[7]);
    float s2 = (p[8] + p[9]) + (p[10] + p[11]);
    float s3 = (p[12] + p[13]) + (p[14] + p[15]);
    float psum = (s0 + s1) + (s2 + s3);
    psum += __shfl_xor(psum, 32, 64);
    lrun += psum;
    // P -> bf16 fragments (cvt_pk + permlane half-swap, verified R4)
    unsigned int w0 = pack_bf16(p[0], p[1]);
    unsigned int w1 = pack_bf16(p[2], p[3]);
    unsigned int w2 = pack_bf16(p[4], p[5]);
    unsigned int w3 = pack_bf16(p[6], p[7]);
    unsigned int w4 = pack_bf16(p[8], p[9]);
    unsigned int w5 = pack_bf16(p[10], p[11]);
    unsigned int w6 = pack_bf16(p[12], p[13]);
    unsigned int w7 = pack_bf16(p[14], p[15]);
    perm32swap(w0, w2);
    perm32swap(w1, w3);
    perm32swap(w4, w6);
    perm32swap(w5, w7);
    bf16x8 pb0 = __builtin_bit_cast(bf16x8, make_uint4(w0, w1, w2, w3));
    bf16x8 pb1 = __builtin_bit_cast(bf16x8, make_uint4(w4, w5, w6, w7));
    // ctx^T[d][q] += sum_k Vt[d][k] * P^T[k][q]
    __builtin_amdgcn_s_setprio(1);
    acc0 = __builtin_amdgcn_mfma_f32_32x32x16_bf16(vA, pb0, acc0, 0, 0, 0);
    acc0 = __builtin_amdgcn_mfma_f32_32x32x16_bf16(vB, pb1, acc0, 0, 0, 0);
    acc1 = __builtin_amdgcn_mfma_f32_32x32x16_bf16(vC, pb0, acc1, 0, 0, 0);
    acc1 = __builtin_amdgcn_mfma_f32_32x32x16_bf16(vD, pb1, acc1, 0, 0, 0);
    __builtin_amdgcn_s_setprio(0);
    __syncthreads();
  }
#undef ASTAGE

  float invl = 1.0f / lrun;
  unsigned short* orow = ctx + ((size_t)b * S_ + qrow) * E_ + head * D_;
#pragma unroll
  for (int g = 0; g < 4; ++g) {
    int d0 = 8 * g + 4 * hh;
    uint2 o0, o1;
    o0.x = pack_bf16(acc0[4 * g + 0] * invl, acc0[4 * g + 1] * invl);
    o0.y = pack_bf16(acc0[4 * g + 2] * invl, acc0[4 * g + 3] * invl);
    o1.x = pack_bf16(acc1[4 * g + 0] * invl, acc1[4 * g + 1] * invl);
    o1.y = pack_bf16(acc1[4 * g + 2] * invl, acc1[4 * g + 3] * invl);
    *reinterpret_cast<uint2*>(orow + d0) = o0;
    *reinterpret_cast<uint2*>(orow + d0 + 32) = o1;
  }
}

extern "C" void kernel_launch(void* const* d_in, const int* in_sizes, int n_in,
                              void* d_out, int out_size, void* d_ws, size_t ws_size,
                              hipStream_t stream) {
  const float* x    = (const float*)d_in[0];
  const float* Wqkv = (const float*)d_in[1];
  const float* bqkv = (const float*)d_in[2];
  const float* Wout = (const float*)d_in[3];
  const float* bout = (const float*)d_in[4];
  float* out = (float*)d_out;

  char* ws = (char*)d_ws;
  unsigned short* qkv_b = (unsigned short*)ws;  ws += (size_t)2 * B_ * H_ * S_ * D_ * 2;  // Q,K
  unsigned short* vT_b  = (unsigned short*)ws;  ws += (size_t)B_ * H_ * D_ * S_ * 2;      // V^T
  unsigned short* ctx_b = (unsigned short*)ws;  ws += (size_t)M_TOT * E_ * 2;
  unsigned short* xb    = (unsigned short*)ws;  ws += (size_t)M_TOT * E_ * 2;
  unsigned short* wqT   = (unsigned short*)ws;  ws += (size_t)N_QKV * K_ * 2;
  unsigned short* woT   = (unsigned short*)ws;

  cvt_k<<<dim3(M_TOT * E_ / 8 / 256), 256, 0, stream>>>(x, xb, M_TOT * E_ / 8);
  tcvt_k<<<dim3(N_QKV / 64, K_ / 64), 256, 0, stream>>>(Wqkv, wqT, K_, N_QKV);
  tcvt_k<<<dim3(E_ / 64, K_ / 64), 256, 0, stream>>>(Wout, woT, K_, E_);

  gemm_k<0><<<dim3(N_QKV / 256, M_TOT / 128), 256, 0, stream>>>(xb, wqT, bqkv, qkv_b, vT_b);
  attn_k<<<dim3(S_ / 128, B_ * H_), 256, 0, stream>>>(qkv_b, vT_b, ctx_b);
  gemm_k<1><<<dim3(E_ / 256, M_TOT / 128), 256, 0, stream>>>(ctx_b, woT, bout, out, nullptr);
}

// Round 7
// 225.207 us; speedup vs baseline: 1.0909x; 1.0909x over previous
//
#include <hip/hip_runtime.h>
#include <math.h>

#define B_ 4
#define S_ 2048
#define E_ 1024
#define H_ 16
#define D_ 64
#define M_TOT 8192
#define N_QKV 3072
#define K_ 1024

typedef __attribute__((ext_vector_type(8))) __bf16 bf16x8;
typedef __attribute__((ext_vector_type(2))) __bf16 bf16x2;
typedef __attribute__((ext_vector_type(8))) unsigned short u16x8;
typedef __attribute__((ext_vector_type(16))) float f32x16;

static __device__ __forceinline__ float bf2f(unsigned short u) {
  union { unsigned int u; float f; } x; x.u = ((unsigned int)u) << 16;
  return x.f;
}
// RNE f32->bf16 pair packed into one u32 (compiler emits v_cvt_pk_bf16_f32)
static __device__ __forceinline__ unsigned int pack_bf16(float lo, float hi) {
  bf16x2 t; t[0] = (__bf16)lo; t[1] = (__bf16)hi;
  return __builtin_bit_cast(unsigned int, t);
}
// v_permlane32_swap_b32: a'={a.lo,b.lo}, b'={a.hi,b.hi} (verified R3->R4)
static __device__ __forceinline__ void perm32swap(unsigned int& a, unsigned int& b) {
  asm volatile("v_permlane32_swap_b32 %0, %1" : "+v"(a), "+v"(b));
}

static __device__ __forceinline__ void gload16(const void* g, void* l) {
  __builtin_amdgcn_global_load_lds(
      (const __attribute__((address_space(1))) void*)g,
      (__attribute__((address_space(3))) void*)l, 16, 0, 0);
}

// ---------------------------------------------------------------------------
// Converters: fp32 -> bf16 (flat), and fp32 [K][N] -> bf16 [N][K] (transpose)
// ---------------------------------------------------------------------------
__global__ __launch_bounds__(256) void cvt_k(const float* __restrict__ in,
                                             unsigned short* __restrict__ out,
                                             int n8) {
  int i = blockIdx.x * 256 + threadIdx.x;
  if (i >= n8) return;
  float4 a = *reinterpret_cast<const float4*>(in + (size_t)i * 8);
  float4 b = *reinterpret_cast<const float4*>(in + (size_t)i * 8 + 4);
  uint4 o;
  o.x = pack_bf16(a.x, a.y); o.y = pack_bf16(a.z, a.w);
  o.z = pack_bf16(b.x, b.y); o.w = pack_bf16(b.z, b.w);
  *reinterpret_cast<uint4*>(out + (size_t)i * 8) = o;
}

__global__ __launch_bounds__(256) void tcvt_k(const float* __restrict__ in,
                                              unsigned short* __restrict__ out,
                                              int K, int N) {
  __shared__ float t[64][65];
  int n0 = blockIdx.x * 64, k0 = blockIdx.y * 64;
  int r = threadIdx.x >> 4, c = (threadIdx.x & 15) * 4;
#pragma unroll
  for (int it = 0; it < 4; ++it) {
    float4 v = *reinterpret_cast<const float4*>(&in[(size_t)(k0 + r + it * 16) * N + n0 + c]);
    t[r + it * 16][c + 0] = v.x; t[r + it * 16][c + 1] = v.y;
    t[r + it * 16][c + 2] = v.z; t[r + it * 16][c + 3] = v.w;
  }
  __syncthreads();
#pragma unroll
  for (int it = 0; it < 4; ++it) {
    int rr = r + it * 16;
    uint2 o;
    o.x = pack_bf16(t[c + 0][rr], t[c + 1][rr]);
    o.y = pack_bf16(t[c + 2][rr], t[c + 3][rr]);
    *reinterpret_cast<uint2*>(&out[(size_t)(n0 + rr) * K + k0 + c]) = o;
  }
}

// ---------------------------------------------------------------------------
// bf16 MFMA GEMM (unchanged from R6): C[M][N] = A[M][K] @ BT[N][K]^T (+bias).
// MODE 0: Q,K -> qkv [2][B][H][S][D]; V -> vT [B][H][D][S].  MODE 1: fp32 C.
// ---------------------------------------------------------------------------
template <int MODE>
__global__ __launch_bounds__(256) void gemm_k(
    const unsigned short* __restrict__ A, const unsigned short* __restrict__ BT,
    const float* __restrict__ bias, void* __restrict__ Cout,
    unsigned short* __restrict__ vT) {
  __shared__ __attribute__((aligned(128))) char lds[2][24576];
  const int tid = threadIdx.x;
  const int wv = tid >> 6, lane = tid & 63;
  const int ln = lane & 31, hh = lane >> 5;
  const int m0 = blockIdx.y * 128, n0 = blockIdx.x * 256;
  const int r4 = lane >> 2, slot = lane & 3;

  const char* Ab = (const char*)A;
  const char* Bb = (const char*)BT;
  size_t a_off[2], b_off[4];
#pragma unroll
  for (int i = 0; i < 2; ++i) {
    int r = wv * 32 + i * 16 + r4;
    a_off[i] = (size_t)(m0 + r) * (K_ * 2) + (size_t)((slot ^ ((r >> 1) & 3)) * 16);
  }
#pragma unroll
  for (int j = 0; j < 4; ++j) {
    int r = wv * 64 + j * 16 + r4;
    b_off[j] = (size_t)(n0 + r) * (K_ * 2) + (size_t)((slot ^ ((r >> 1) & 3)) * 16);
  }

  f32x16 acc[4][2];
#pragma unroll
  for (int gr = 0; gr < 4; ++gr)
#pragma unroll
    for (int gc = 0; gc < 2; ++gc)
#pragma unroll
      for (int e = 0; e < 16; ++e) acc[gr][gc][e] = 0.f;

#define STAGE(dst, tt)                                                        \
  do {                                                                        \
    char* _d = (dst);                                                         \
    size_t _ko = (size_t)(tt) * 64;                                           \
    _Pragma("unroll") for (int i = 0; i < 2; ++i)                             \
        gload16(Ab + a_off[i] + _ko, _d + (wv * 32 + i * 16) * 64);           \
    _Pragma("unroll") for (int j = 0; j < 4; ++j)                             \
        gload16(Bb + b_off[j] + _ko, _d + 8192 + (wv * 64 + j * 16) * 64);    \
  } while (0)

  STAGE(&lds[0][0], 0);
  __syncthreads();
  for (int t = 0; t < K_ / 32; ++t) {
    char* cur = &lds[t & 1][0];
    char* nxt = &lds[(t + 1) & 1][0];
    if (t + 1 < K_ / 32) STAGE(nxt, t + 1);
#pragma unroll
    for (int s = 0; s < 2; ++s) {
      const int cb = s * 32 + hh * 16;
      bf16x8 af[4], bfr[2];
#pragma unroll
      for (int gr = 0; gr < 4; ++gr) {
        int row = gr * 32 + ln;
        af[gr] = *reinterpret_cast<const bf16x8*>(
            cur + row * 64 + (cb ^ (((row >> 1) & 3) << 4)));
      }
#pragma unroll
      for (int gc = 0; gc < 2; ++gc) {
        int row = wv * 64 + gc * 32 + ln;
        bfr[gc] = *reinterpret_cast<const bf16x8*>(
            cur + 8192 + row * 64 + (cb ^ (((row >> 1) & 3) << 4)));
      }
#pragma unroll
      for (int gr = 0; gr < 4; ++gr)
#pragma unroll
        for (int gc = 0; gc < 2; ++gc)
          acc[gr][gc] = __builtin_amdgcn_mfma_f32_32x32x16_bf16(
              af[gr], bfr[gc], acc[gr][gc], 0, 0, 0);
    }
    __syncthreads();
  }
#undef STAGE

  const int ncol0 = n0 + wv * 64;
  if (MODE == 0) {
    unsigned short* qkv = (unsigned short*)Cout;
#pragma unroll
    for (int gc = 0; gc < 2; ++gc) {
      int n = ncol0 + gc * 32 + ln;
      float bv = bias[n];
      int which = n >> 10, h = (n >> 6) & 15, d = n & 63;
      if (which < 2) {  // Q or K: [which][bi][h][si][d]
        unsigned short* base =
            qkv + (((size_t)which * B_ * H_ + h) * S_) * D_ + d;
#pragma unroll
        for (int gr = 0; gr < 4; ++gr)
#pragma unroll
          for (int r = 0; r < 16; r += 2) {
            int m = m0 + gr * 32 + 4 * hh + (r & 3) + 8 * (r >> 2);
            unsigned int w = pack_bf16(acc[gr][gc][r] + bv, acc[gr][gc][r + 1] + bv);
            int bi = m >> 11, si = m & 2047;
            size_t off = ((size_t)bi * H_ * S_ + si) * D_;
            base[off] = (unsigned short)w;
            base[off + D_] = (unsigned short)(w >> 16);
          }
      } else {  // V: transposed store vT[bi][h][d][si]
        unsigned short* vbase = vT + ((size_t)h * D_ + d) * S_;
#pragma unroll
        for (int gr = 0; gr < 4; ++gr)
#pragma unroll
          for (int rq = 0; rq < 4; ++rq) {
            int mb = m0 + gr * 32 + 4 * hh + 8 * rq;
            int bi = mb >> 11, si = mb & 2047;
            uint2 w;
            w.x = pack_bf16(acc[gr][gc][rq * 4 + 0] + bv, acc[gr][gc][rq * 4 + 1] + bv);
            w.y = pack_bf16(acc[gr][gc][rq * 4 + 2] + bv, acc[gr][gc][rq * 4 + 3] + bv);
            *reinterpret_cast<uint2*>(vbase + (size_t)bi * H_ * D_ * S_ + si) = w;
          }
      }
    }
  } else {
    float* out = (float*)Cout;
#pragma unroll
    for (int gc = 0; gc < 2; ++gc) {
      int n = ncol0 + gc * 32 + ln;
      float bv = bias[n];
#pragma unroll
      for (int gr = 0; gr < 4; ++gr)
#pragma unroll
        for (int r = 0; r < 16; ++r) {
          int m = m0 + gr * 32 + 4 * hh + (r & 3) + 8 * (r >> 2);
          out[(size_t)m * E_ + n] = acc[gr][gc][r] + bv;
        }
    }
  }
}

// ---------------------------------------------------------------------------
// bf16 MFMA flash attention. R7: raw v_exp_f32 via __builtin_amdgcn_exp2f
// (replaces OCML exp2f expansion — the dominant VALU cost), and -mrun folded
// into the QK^T accumulator init (deletes 16 subs/step; defer-max test is
// relative: tm <= 8). mrun starts at 0 (cancellation-safe; first-step
// overflow of the 8-threshold takes the rescale path).
// ---------------------------------------------------------------------------
__global__ __launch_bounds__(256, 4) void attn_k(
    const unsigned short* __restrict__ qkv, const unsigned short* __restrict__ vT,
    unsigned short* __restrict__ ctx) {
  __shared__ __attribute__((aligned(128))) char lds[2][8192];  // 4KB K + 4KB Vt
  const int tid = threadIdx.x;
  const int wv = tid >> 6;
  const int lane = tid & 63;
  const int ln = lane & 31;
  const int hh = lane >> 5;
  const int q0 = blockIdx.x * 128;
  const int bh = blockIdx.y;
  const int b = bh >> 4, head = bh & 15;
  const size_t SZ = (size_t)B_ * H_ * S_ * D_;
  const size_t plane = ((size_t)b * H_ + head) * (size_t)S_ * D_;
  const unsigned short* Qp = qkv + plane;
  const unsigned short* Kp = qkv + SZ + plane;
  const unsigned short* Vp = vT + ((size_t)b * H_ + head) * (size_t)D_ * S_;

  // Q in registers, pre-scaled by (1/8)*log2(e)
  const float SC = 0.125f * 1.4426950408889634f;
  const int qrow = q0 + wv * 32 + ln;
  bf16x8 qf[4];
#pragma unroll
  for (int db = 0; db < 4; ++db) {
    u16x8 qr = *reinterpret_cast<const u16x8*>(Qp + (size_t)qrow * D_ + db * 16 + hh * 8);
    bf16x8 qs;
#pragma unroll
    for (int j = 0; j < 8; ++j) qs[j] = (__bf16)(bf2f(qr[j]) * SC);
    qf[db] = qs;
  }

  // staging source offsets (elements); LDS dests are linear tid*16
  const size_t ksrc = (size_t)(tid >> 3) * 64 +
                      (size_t)(((tid & 7) ^ ((tid >> 3) & 7)) * 8);
  const size_t vsrc = (size_t)(tid >> 2) * S_ +
                      (size_t)(((tid & 3) ^ ((tid >> 3) & 3)) * 8);

#define ASTAGE(bsel, tt)                                                      \
  do {                                                                        \
    char* _d = &lds[(bsel)][0];                                               \
    gload16(Kp + (size_t)(tt) * 2048 + ksrc, _d + tid * 16);                  \
    gload16(Vp + (size_t)(tt) * 32 + vsrc, _d + 4096 + tid * 16);             \
  } while (0)

  ASTAGE(0, 0);
  __syncthreads();

  f32x16 acc0, acc1;
#pragma unroll
  for (int e = 0; e < 16; ++e) { acc0[e] = 0.f; acc1[e] = 0.f; }
  float mrun = 0.f, lrun = 0.f;  // mrun folded into st init (relative scheme)
  const int xo = (ln >> 1) & 3;

  for (int t = 0; t < 64; ++t) {
    const int cb = t & 1;
    if (t + 1 < 64) ASTAGE(cb ^ 1, t + 1);
    const char* cur = &lds[cb][0];
    // QK^T -> S^T[key][q] - mrun   (C-init = -mrun)
    f32x16 st;
    const float nm = -mrun;
#pragma unroll
    for (int e = 0; e < 16; ++e) st[e] = nm;
    __builtin_amdgcn_s_setprio(1);
#pragma unroll
    for (int db = 0; db < 4; ++db) {
      bf16x8 kf = *reinterpret_cast<const bf16x8*>(
          cur + ln * 128 + ((((db << 1) | hh) ^ (ln & 7)) << 4));
      st = __builtin_amdgcn_mfma_f32_32x32x16_bf16(kf, qf[db], st, 0, 0, 0);
    }
    __builtin_amdgcn_s_setprio(0);
    // Vt fragments (issue early; lgkm latency hides under softmax VALU)
    const char* vb_ = cur + 4096;
    bf16x8 vA = *reinterpret_cast<const bf16x8*>(vb_ + ln * 64 + ((hh ^ xo) << 4));
    bf16x8 vB = *reinterpret_cast<const bf16x8*>(vb_ + ln * 64 + (((2 + hh) ^ xo) << 4));
    bf16x8 vC = *reinterpret_cast<const bf16x8*>(vb_ + (ln + 32) * 64 + ((hh ^ xo) << 4));
    bf16x8 vD = *reinterpret_cast<const bf16x8*>(vb_ + (ln + 32) * 64 + (((2 + hh) ^ xo) << 4));
    // relative row max over 32 keys
    float m1 = fmaxf(fmaxf(st[0], st[1]), st[2]);
    float m2 = fmaxf(fmaxf(st[3], st[4]), st[5]);
    float m3 = fmaxf(fmaxf(st[6], st[7]), st[8]);
    float m4 = fmaxf(fmaxf(st[9], st[10]), st[11]);
    float m5 = fmaxf(fmaxf(st[12], st[13]), st[14]);
    float tm = fmaxf(fmaxf(fmaxf(m1, m2), fmaxf(m3, m4)), fmaxf(m5, st[15]));
    tm = fmaxf(tm, __shfl_xor(tm, 32, 64));
    if (!__all(tm <= 8.0f)) {  // defer-max (T13), relative test
      float d = fmaxf(tm, 0.f);
      float alpha = __builtin_amdgcn_exp2f(-d);
      mrun += d;
      lrun *= alpha;
      acc0 *= alpha;
      acc1 *= alpha;
#pragma unroll
      for (int r = 0; r < 16; ++r) st[r] -= d;
    }
    float p[16];
#pragma unroll
    for (int r = 0; r < 16; ++r) p[r] = __builtin_amdgcn_exp2f(st[r]);
    float s0 = (p[0] + p[1]) + (p[2] + p[3]);
    float s1 = (p[4] + p[5]) + (p[6] + p[7]);
    float s2 = (p[8] + p[9]) + (p[10] + p[11]);
    float s3 = (p[12] + p[13]) + (p[14] + p[15]);
    float psum = (s0 + s1) + (s2 + s3);
    psum += __shfl_xor(psum, 32, 64);
    lrun += psum;
    // P -> bf16 fragments (cvt_pk + permlane half-swap, verified R4)
    unsigned int w0 = pack_bf16(p[0], p[1]);
    unsigned int w1 = pack_bf16(p[2], p[3]);
    unsigned int w2 = pack_bf16(p[4], p[5]);
    unsigned int w3 = pack_bf16(p[6], p[7]);
    unsigned int w4 = pack_bf16(p[8], p[9]);
    unsigned int w5 = pack_bf16(p[10], p[11]);
    unsigned int w6 = pack_bf16(p[12], p[13]);
    unsigned int w7 = pack_bf16(p[14], p[15]);
    perm32swap(w0, w2);
    perm32swap(w1, w3);
    perm32swap(w4, w6);
    perm32swap(w5, w7);
    bf16x8 pb0 = __builtin_bit_cast(bf16x8, make_uint4(w0, w1, w2, w3));
    bf16x8 pb1 = __builtin_bit_cast(bf16x8, make_uint4(w4, w5, w6, w7));
    // ctx^T[d][q] += sum_k Vt[d][k] * P^T[k][q]
    __builtin_amdgcn_s_setprio(1);
    acc0 = __builtin_amdgcn_mfma_f32_32x32x16_bf16(vA, pb0, acc0, 0, 0, 0);
    acc0 = __builtin_amdgcn_mfma_f32_32x32x16_bf16(vB, pb1, acc0, 0, 0, 0);
    acc1 = __builtin_amdgcn_mfma_f32_32x32x16_bf16(vC, pb0, acc1, 0, 0, 0);
    acc1 = __builtin_amdgcn_mfma_f32_32x32x16_bf16(vD, pb1, acc1, 0, 0, 0);
    __builtin_amdgcn_s_setprio(0);
    __syncthreads();
  }
#undef ASTAGE

  float invl = 1.0f / lrun;
  unsigned short* orow = ctx + ((size_t)b * S_ + qrow) * E_ + head * D_;
#pragma unroll
  for (int g = 0; g < 4; ++g) {
    int d0 = 8 * g + 4 * hh;
    uint2 o0, o1;
    o0.x = pack_bf16(acc0[4 * g + 0] * invl, acc0[4 * g + 1] * invl);
    o0.y = pack_bf16(acc0[4 * g + 2] * invl, acc0[4 * g + 3] * invl);
    o1.x = pack_bf16(acc1[4 * g + 0] * invl, acc1[4 * g + 1] * invl);
    o1.y = pack_bf16(acc1[4 * g + 2] * invl, acc1[4 * g + 3] * invl);
    *reinterpret_cast<uint2*>(orow + d0) = o0;
    *reinterpret_cast<uint2*>(orow + d0 + 32) = o1;
  }
}

extern "C" void kernel_launch(void* const* d_in, const int* in_sizes, int n_in,
                              void* d_out, int out_size, void* d_ws, size_t ws_size,
                              hipStream_t stream) {
  const float* x    = (const float*)d_in[0];
  const float* Wqkv = (const float*)d_in[1];
  const float* bqkv = (const float*)d_in[2];
  const float* Wout = (const float*)d_in[3];
  const float* bout = (const float*)d_in[4];
  float* out = (float*)d_out;

  char* ws = (char*)d_ws;
  unsigned short* qkv_b = (unsigned short*)ws;  ws += (size_t)2 * B_ * H_ * S_ * D_ * 2;  // Q,K
  unsigned short* vT_b  = (unsigned short*)ws;  ws += (size_t)B_ * H_ * D_ * S_ * 2;      // V^T
  unsigned short* ctx_b = (unsigned short*)ws;  ws += (size_t)M_TOT * E_ * 2;
  unsigned short* xb    = (unsigned short*)ws;  ws += (size_t)M_TOT * E_ * 2;
  unsigned short* wqT   = (unsigned short*)ws;  ws += (size_t)N_QKV * K_ * 2;
  unsigned short* woT   = (unsigned short*)ws;

  cvt_k<<<dim3(M_TOT * E_ / 8 / 256), 256, 0, stream>>>(x, xb, M_TOT * E_ / 8);
  tcvt_k<<<dim3(N_QKV / 64, K_ / 64), 256, 0, stream>>>(Wqkv, wqT, K_, N_QKV);
  tcvt_k<<<dim3(E_ / 64, K_ / 64), 256, 0, stream>>>(Wout, woT, K_, E_);

  gemm_k<0><<<dim3(N_QKV / 256, M_TOT / 128), 256, 0, stream>>>(xb, wqT, bqkv, qkv_b, vT_b);
  attn_k<<<dim3(S_ / 128, B_ * H_), 256, 0, stream>>>(qkv_b, vT_b, ctx_b);
  gemm_k<1><<<dim3(E_ / 256, M_TOT / 128), 256, 0, stream>>>(ctx_b, woT, bout, out, nullptr);
}